// Round 6
// baseline (354.022 us; speedup 1.0000x reference)
//
#include <hip/hip_runtime.h>
#include <hip/hip_fp16.h>

// VoxelGrid trilinear sampling, MI355X.
// Round 6: int8 cell records. The gather kernel is bound by the random-64B
// L2-fill ceiling (~3.6 TB/s measured across R1/R4/R5). Fetch = x(100MB) +
// 537MB gather-line-demand * miss(table footprint vs 4MB per-XCD L2).
// Shrinking the record 16B -> 8B (8x int8 corners, one global scale) halves
// the table to 15.5 MB -> L2 hit ~13% -> ~26% -> fetch ~512 -> ~450 MB.

constexpr int SX = 200, SY = 200, SZ = 50;
constexpr int NVOX = SX * SY * SZ;            // 2,000,000
constexpr int CX = SX - 1, CY = SY - 1, CZ = SZ - 1;  // 199,199,49
constexpr long long NCELL = (long long)CX * CY * CZ;  // 1,940,449
constexpr int PPT = 4;                        // points per thread
constexpr int BLK = 256;
constexpr int PPB = BLK * PPT;                // 1024 points per block

// ws layout: [0, NCELL*8)  int8 cell records (uint2 each)
//            [NCELL*8, +4) uint scale slot (bit pattern of absmax(grid))

__global__ __launch_bounds__(256) void grid_absmax(
    const float* __restrict__ grid, unsigned int* __restrict__ scale_u)
{
    int i = blockIdx.x * 256 + threadIdx.x;
    unsigned int u = 0;
    if (i < NVOX) u = __float_as_uint(grid[i]) & 0x7fffffffu;
    // wave reduce (abs-float bit pattern order == float order for >=0)
    #pragma unroll
    for (int off = 32; off > 0; off >>= 1)
        u = max(u, (unsigned int)__shfl_xor((int)u, off, 64));
    __shared__ unsigned int wmax[4];
    int lane = threadIdx.x & 63, wid = threadIdx.x >> 6;
    if (lane == 0) wmax[wid] = u;
    __syncthreads();
    if (threadIdx.x == 0) {
        unsigned int m = max(max(wmax[0], wmax[1]), max(wmax[2], wmax[3]));
        atomicMax(scale_u, m);
    }
}

__global__ __launch_bounds__(256) void build_cells_i8(
    const float* __restrict__ grid, uint2* __restrict__ rec,
    const unsigned int* __restrict__ scale_u)
{
    long long i = (long long)blockIdx.x * 256 + threadIdx.x;
    if (i >= NCELL) return;
    float absmax = __uint_as_float(*scale_u);
    float inv = (absmax > 0.0f) ? 127.0f / absmax : 0.0f;

    int cz = (int)(i % CZ);
    long long tmp = i / CZ;
    int cy = (int)(tmp % CY);
    int cx = (int)(tmp / CY);

    const float* g00 = grid + (cx * SY + cy) * SZ + cz;  // (x0,y0,z)
    const float* g01 = g00 + SZ;        // y+1
    const float* g10 = g00 + SY * SZ;   // x+1
    const float* g11 = g10 + SZ;

    float v[8] = { g00[0], g00[1], g01[0], g01[1],
                   g10[0], g10[1], g11[0], g11[1] };
    unsigned int lo = 0, hi = 0;
    #pragma unroll
    for (int k = 0; k < 4; ++k) {
        int q = (int)rintf(v[k] * inv);
        q = min(max(q, -127), 127);
        lo |= ((unsigned int)(q & 0xff)) << (8 * k);
    }
    #pragma unroll
    for (int k = 0; k < 4; ++k) {
        int q = (int)rintf(v[4 + k] * inv);
        q = min(max(q, -127), 127);
        hi |= ((unsigned int)(q & 0xff)) << (8 * k);
    }
    rec[i] = make_uint2(lo, hi);
}

__device__ __forceinline__ float sb(unsigned int w, int k)  // signed byte k -> float
{
    return (float)((int)(w << (24 - 8 * k)) >> 24);
}

__global__ __launch_bounds__(256) void voxel_trilinear_i8(
    const float* __restrict__ x,      // [N,3]
    const uint2* __restrict__ rec,    // [NCELL] int8 cell records
    const unsigned int* __restrict__ scale_u,
    float* __restrict__ out,          // [2*N]: sigma | alpha
    int n)
{
    __shared__ float xs[3 * PPB];     // 12 KB
    int tid = threadIdx.x;
    long long base = (long long)blockIdx.x * PPB;
    float s = __uint_as_float(*scale_u) * (1.0f / 127.0f);

    if (base + PPB <= n) {
        const float4* xg = (const float4*)(x + base * 3);
        float4* xl = (float4*)xs;
        #pragma unroll
        for (int j = 0; j < 3; ++j)
            xl[tid + BLK * j] = xg[tid + BLK * j];
    } else {
        for (int j = tid; j < 3 * PPB; j += BLK) {
            long long g = base * 3 + j;
            xs[j] = (g < 3LL * n) ? x[g] : 0.0f;
        }
    }
    __syncthreads();

    long long cell[PPT];
    float ux[PPT], uy[PPT], uz[PPT];
    bool  valid[PPT];

    #pragma unroll
    for (int k = 0; k < PPT; ++k) {
        int p = tid + BLK * k;
        float ix = (xs[3 * p + 0] + 4.0f) * 25.0f;
        float iy = (xs[3 * p + 1] + 4.0f) * 25.0f;
        float iz = (xs[3 * p + 2] + 1.0f) * 25.0f;
        valid[k] = (ix >= 0.0f) & (ix <= (float)(SX - 1)) &
                   (iy >= 0.0f) & (iy <= (float)(SY - 1)) &
                   (iz >= 0.0f) & (iz <= (float)(SZ - 1));
        int cx = min(max((int)floorf(ix), 0), SX - 2);
        int cy = min(max((int)floorf(iy), 0), SY - 2);
        int cz = min(max((int)floorf(iz), 0), SZ - 2);
        ux[k] = ix - (float)cx;
        uy[k] = iy - (float)cy;
        uz[k] = iz - (float)cz;
        cell[k] = (long long)(cx * CY + cy) * CZ + cz;
    }

    uint2 pk[PPT];
    #pragma unroll
    for (int k = 0; k < PPT; ++k)
        pk[k] = rec[cell[k]];

    #pragma unroll
    for (int k = 0; k < PPT; ++k) {
        unsigned int lo = pk[k].x, hi = pk[k].y;
        // bytes: lo = v000 v001 v010 v011 ; hi = v100 v101 v110 v111
        float vz = 1.0f - uz[k], vy = 1.0f - uy[k], vx = 1.0f - ux[k];
        float c00 = sb(lo, 0) * vz + sb(lo, 1) * uz[k];
        float c01 = sb(lo, 2) * vz + sb(lo, 3) * uz[k];
        float c10 = sb(hi, 0) * vz + sb(hi, 1) * uz[k];
        float c11 = sb(hi, 2) * vz + sb(hi, 3) * uz[k];
        float c0 = c00 * vy + c01 * uy[k];
        float c1 = c10 * vy + c11 * uy[k];
        float acc = (c0 * vx + c1 * ux[k]) * s;   // single dequant multiply

        long long i = base + tid + BLK * k;
        if (i < n) {
            out[i] = valid[k] ? acc : 0.0f;  // sigma
            out[n + i] = 0.0f;               // alpha (do_alpha=False)
        }
    }
}

// ---- fallback (fp16 z-pair table, 4 MB) for small ws ----
__global__ __launch_bounds__(256) void convert_grid_fp16(
    const float* __restrict__ grid, __half* __restrict__ t)
{
    int i = blockIdx.x * 256 + threadIdx.x;
    if (i < NVOX) t[i] = __float2half(grid[i]);
}

__device__ __forceinline__ float2 ldpair(const __half* __restrict__ t, int idx)
{
    __half2 h;
    __builtin_memcpy(&h, t + idx, sizeof(__half2));
    return __half22float2(h);
}

__global__ __launch_bounds__(256) void voxel_trilinear_pair(
    const float* __restrict__ x, const __half* __restrict__ t,
    float* __restrict__ out, int n)
{
    int i = blockIdx.x * 256 + threadIdx.x;
    if (i >= n) return;
    float ix = (x[3 * i + 0] + 4.0f) * 25.0f;
    float iy = (x[3 * i + 1] + 4.0f) * 25.0f;
    float iz = (x[3 * i + 2] + 1.0f) * 25.0f;
    bool valid = (ix >= 0.0f) & (ix <= (float)(SX - 1)) &
                 (iy >= 0.0f) & (iy <= (float)(SY - 1)) &
                 (iz >= 0.0f) & (iz <= (float)(SZ - 1));
    float fx = floorf(ix), fy = floorf(iy), fz = floorf(iz);
    int ax = min(max((int)fx, 0), SX - 1);
    int ay = min(max((int)fy, 0), SY - 1);
    int bx = min(ax + 1, SX - 1);
    int by = min(ay + 1, SY - 1);
    int zc = min(max((int)fz, 0), SZ - 2);
    float u = iz - (float)zc, su = 1.0f - u;
    float tx = ix - fx, ty = iy - fy;
    float sx = 1.0f - tx, sy = 1.0f - ty;
    int r00 = (ax * SY + ay) * SZ + zc;
    int r01 = (ax * SY + by) * SZ + zc;
    int r10 = (bx * SY + ay) * SZ + zc;
    int r11 = (bx * SY + by) * SZ + zc;
    float2 p00 = ldpair(t, r00), p01 = ldpair(t, r01);
    float2 p10 = ldpair(t, r10), p11 = ldpair(t, r11);
    float c00 = p00.x * su + p00.y * u;
    float c01 = p01.x * su + p01.y * u;
    float c10 = p10.x * su + p10.y * u;
    float c11 = p11.x * su + p11.y * u;
    float c0 = c00 * sy + c01 * ty;
    float c1 = c10 * sy + c11 * ty;
    out[i] = valid ? (c0 * sx + c1 * tx) : 0.0f;
    out[n + i] = 0.0f;
}

extern "C" void kernel_launch(void* const* d_in, const int* in_sizes, int n_in,
                              void* d_out, int out_size, void* d_ws, size_t ws_size,
                              hipStream_t stream) {
    const float* x = (const float*)d_in[0];
    const float* grid = (const float*)d_in[1];
    float* out = (float*)d_out;
    int n = in_sizes[0] / 3;  // 8388608

    size_t rec_bytes = (size_t)NCELL * sizeof(uint2);
    if (ws_size >= rec_bytes + 4) {
        uint2* rec = (uint2*)d_ws;
        unsigned int* scale_u = (unsigned int*)((char*)d_ws + rec_bytes);
        hipMemsetAsync(scale_u, 0, 4, stream);  // ws is poisoned 0xAA
        grid_absmax<<<(NVOX + 255) / 256, 256, 0, stream>>>(grid, scale_u);
        build_cells_i8<<<(int)((NCELL + 255) / 256), 256, 0, stream>>>(grid, rec, scale_u);
        int blocks = (n + PPB - 1) / PPB;
        voxel_trilinear_i8<<<blocks, BLK, 0, stream>>>(x, rec, scale_u, out, n);
    } else if (ws_size >= (size_t)NVOX * sizeof(__half)) {
        __half* t = (__half*)d_ws;
        convert_grid_fp16<<<(NVOX + 255) / 256, 256, 0, stream>>>(grid, t);
        voxel_trilinear_pair<<<(n + 255) / 256, 256, 0, stream>>>(x, t, out, n);
    }
}

// Round 7
// 272.203 us; speedup vs baseline: 1.3006x; 1.3006x over previous
//
#include <hip/hip_runtime.h>
#include <hip/hip_fp16.h>

// VoxelGrid trilinear sampling, MI355X.
// Round 7: same int8 cell-record gather (at the measured ~3.9 TB/s random-
// 64B-fill ceiling: x 100MB + fills ~350MB + writes 67MB ~= 135us), but fix
// the R6 prologue regression: grid_absmax did 7813 same-address atomicMax
// (~90us serialized). Now grid-stride, float4, ONE atomic per block (512).

constexpr int SX = 200, SY = 200, SZ = 50;
constexpr int NVOX = SX * SY * SZ;            // 2,000,000 (divisible by 4)
constexpr int CX = SX - 1, CY = SY - 1, CZ = SZ - 1;  // 199,199,49
constexpr int NCELL = CX * CY * CZ;           // 1,940,449
constexpr int PPT = 4;                        // points per thread
constexpr int BLK = 256;
constexpr int PPB = BLK * PPT;                // 1024 points per block

// ws layout: [0, NCELL*8)  int8 cell records (uint2 each)
//            [NCELL*8, +4) uint scale slot (bit pattern of absmax(grid))

__global__ __launch_bounds__(256) void grid_absmax(
    const float4* __restrict__ g4, unsigned int* __restrict__ scale_u)
{
    int tid = blockIdx.x * 256 + threadIdx.x;
    int stride = gridDim.x * 256;
    unsigned int u = 0;
    for (int i = tid; i < NVOX / 4; i += stride) {
        float4 v = g4[i];
        u = max(u, __float_as_uint(v.x) & 0x7fffffffu);
        u = max(u, __float_as_uint(v.y) & 0x7fffffffu);
        u = max(u, __float_as_uint(v.z) & 0x7fffffffu);
        u = max(u, __float_as_uint(v.w) & 0x7fffffffu);
    }
    // wave reduce (abs-float bit pattern order == float order for >=0)
    #pragma unroll
    for (int off = 32; off > 0; off >>= 1)
        u = max(u, (unsigned int)__shfl_xor((int)u, off, 64));
    __shared__ unsigned int wmax[4];
    int lane = threadIdx.x & 63, wid = threadIdx.x >> 6;
    if (lane == 0) wmax[wid] = u;
    __syncthreads();
    if (threadIdx.x == 0) {
        unsigned int m = max(max(wmax[0], wmax[1]), max(wmax[2], wmax[3]));
        atomicMax(scale_u, m);   // one atomic per block (512 total)
    }
}

__global__ __launch_bounds__(256) void build_cells_i8(
    const float* __restrict__ grid, uint2* __restrict__ rec,
    const unsigned int* __restrict__ scale_u)
{
    int i = blockIdx.x * 256 + threadIdx.x;
    if (i >= NCELL) return;
    float absmax = __uint_as_float(*scale_u);
    float inv = (absmax > 0.0f) ? 127.0f / absmax : 0.0f;

    int cz = i % CZ;
    int tmp = i / CZ;
    int cy = tmp % CY;
    int cx = tmp / CY;

    const float* g00 = grid + (cx * SY + cy) * SZ + cz;  // (x0,y0,z)
    const float* g01 = g00 + SZ;        // y+1
    const float* g10 = g00 + SY * SZ;   // x+1
    const float* g11 = g10 + SZ;

    float v[8] = { g00[0], g00[1], g01[0], g01[1],
                   g10[0], g10[1], g11[0], g11[1] };
    unsigned int lo = 0, hi = 0;
    #pragma unroll
    for (int k = 0; k < 4; ++k) {
        int q = (int)rintf(v[k] * inv);
        q = min(max(q, -127), 127);
        lo |= ((unsigned int)(q & 0xff)) << (8 * k);
    }
    #pragma unroll
    for (int k = 0; k < 4; ++k) {
        int q = (int)rintf(v[4 + k] * inv);
        q = min(max(q, -127), 127);
        hi |= ((unsigned int)(q & 0xff)) << (8 * k);
    }
    rec[i] = make_uint2(lo, hi);
}

__device__ __forceinline__ float sb(unsigned int w, int k)  // signed byte k -> float
{
    return (float)((int)(w << (24 - 8 * k)) >> 24);
}

__global__ __launch_bounds__(256) void voxel_trilinear_i8(
    const float* __restrict__ x,      // [N,3]
    const uint2* __restrict__ rec,    // [NCELL] int8 cell records
    const unsigned int* __restrict__ scale_u,
    float* __restrict__ out,          // [2*N]: sigma | alpha
    int n)
{
    __shared__ float xs[3 * PPB];     // 12 KB
    int tid = threadIdx.x;
    long long base = (long long)blockIdx.x * PPB;
    float s = __uint_as_float(*scale_u) * (1.0f / 127.0f);

    if (base + PPB <= n) {
        const float4* xg = (const float4*)(x + base * 3);
        float4* xl = (float4*)xs;
        #pragma unroll
        for (int j = 0; j < 3; ++j)
            xl[tid + BLK * j] = xg[tid + BLK * j];
    } else {
        for (int j = tid; j < 3 * PPB; j += BLK) {
            long long g = base * 3 + j;
            xs[j] = (g < 3LL * n) ? x[g] : 0.0f;
        }
    }
    __syncthreads();

    int   cell[PPT];
    float ux[PPT], uy[PPT], uz[PPT];
    bool  valid[PPT];

    #pragma unroll
    for (int k = 0; k < PPT; ++k) {
        int p = tid + BLK * k;
        float ix = (xs[3 * p + 0] + 4.0f) * 25.0f;
        float iy = (xs[3 * p + 1] + 4.0f) * 25.0f;
        float iz = (xs[3 * p + 2] + 1.0f) * 25.0f;
        valid[k] = (ix >= 0.0f) & (ix <= (float)(SX - 1)) &
                   (iy >= 0.0f) & (iy <= (float)(SY - 1)) &
                   (iz >= 0.0f) & (iz <= (float)(SZ - 1));
        int cx = min(max((int)floorf(ix), 0), SX - 2);
        int cy = min(max((int)floorf(iy), 0), SY - 2);
        int cz = min(max((int)floorf(iz), 0), SZ - 2);
        ux[k] = ix - (float)cx;
        uy[k] = iy - (float)cy;
        uz[k] = iz - (float)cz;
        cell[k] = (cx * CY + cy) * CZ + cz;
    }

    uint2 pk[PPT];
    #pragma unroll
    for (int k = 0; k < PPT; ++k)
        pk[k] = rec[cell[k]];

    #pragma unroll
    for (int k = 0; k < PPT; ++k) {
        unsigned int lo = pk[k].x, hi = pk[k].y;
        // bytes: lo = v000 v001 v010 v011 ; hi = v100 v101 v110 v111
        float vz = 1.0f - uz[k], vy = 1.0f - uy[k], vx = 1.0f - ux[k];
        float c00 = sb(lo, 0) * vz + sb(lo, 1) * uz[k];
        float c01 = sb(lo, 2) * vz + sb(lo, 3) * uz[k];
        float c10 = sb(hi, 0) * vz + sb(hi, 1) * uz[k];
        float c11 = sb(hi, 2) * vz + sb(hi, 3) * uz[k];
        float c0 = c00 * vy + c01 * uy[k];
        float c1 = c10 * vy + c11 * uy[k];
        float acc = (c0 * vx + c1 * ux[k]) * s;   // single dequant multiply

        long long i = base + tid + BLK * k;
        if (i < n) {
            out[i] = valid[k] ? acc : 0.0f;  // sigma
            out[n + i] = 0.0f;               // alpha (do_alpha=False)
        }
    }
}

// ---- fallback (fp16 z-pair table, 4 MB) for small ws ----
__global__ __launch_bounds__(256) void convert_grid_fp16(
    const float* __restrict__ grid, __half* __restrict__ t)
{
    int i = blockIdx.x * 256 + threadIdx.x;
    if (i < NVOX) t[i] = __float2half(grid[i]);
}

__device__ __forceinline__ float2 ldpair(const __half* __restrict__ t, int idx)
{
    __half2 h;
    __builtin_memcpy(&h, t + idx, sizeof(__half2));
    return __half22float2(h);
}

__global__ __launch_bounds__(256) void voxel_trilinear_pair(
    const float* __restrict__ x, const __half* __restrict__ t,
    float* __restrict__ out, int n)
{
    int i = blockIdx.x * 256 + threadIdx.x;
    if (i >= n) return;
    float ix = (x[3 * i + 0] + 4.0f) * 25.0f;
    float iy = (x[3 * i + 1] + 4.0f) * 25.0f;
    float iz = (x[3 * i + 2] + 1.0f) * 25.0f;
    bool valid = (ix >= 0.0f) & (ix <= (float)(SX - 1)) &
                 (iy >= 0.0f) & (iy <= (float)(SY - 1)) &
                 (iz >= 0.0f) & (iz <= (float)(SZ - 1));
    float fx = floorf(ix), fy = floorf(iy), fz = floorf(iz);
    int ax = min(max((int)fx, 0), SX - 1);
    int ay = min(max((int)fy, 0), SY - 1);
    int bx = min(ax + 1, SX - 1);
    int by = min(ay + 1, SY - 1);
    int zc = min(max((int)fz, 0), SZ - 2);
    float u = iz - (float)zc, su = 1.0f - u;
    float tx = ix - fx, ty = iy - fy;
    float sx = 1.0f - tx, sy = 1.0f - ty;
    int r00 = (ax * SY + ay) * SZ + zc;
    int r01 = (ax * SY + by) * SZ + zc;
    int r10 = (bx * SY + ay) * SZ + zc;
    int r11 = (bx * SY + by) * SZ + zc;
    float2 p00 = ldpair(t, r00), p01 = ldpair(t, r01);
    float2 p10 = ldpair(t, r10), p11 = ldpair(t, r11);
    float c00 = p00.x * su + p00.y * u;
    float c01 = p01.x * su + p01.y * u;
    float c10 = p10.x * su + p10.y * u;
    float c11 = p11.x * su + p11.y * u;
    float c0 = c00 * sy + c01 * ty;
    float c1 = c10 * sy + c11 * ty;
    out[i] = valid ? (c0 * sx + c1 * tx) : 0.0f;
    out[n + i] = 0.0f;
}

extern "C" void kernel_launch(void* const* d_in, const int* in_sizes, int n_in,
                              void* d_out, int out_size, void* d_ws, size_t ws_size,
                              hipStream_t stream) {
    const float* x = (const float*)d_in[0];
    const float* grid = (const float*)d_in[1];
    float* out = (float*)d_out;
    int n = in_sizes[0] / 3;  // 8388608

    size_t rec_bytes = (size_t)NCELL * sizeof(uint2);
    if (ws_size >= rec_bytes + 4) {
        uint2* rec = (uint2*)d_ws;
        unsigned int* scale_u = (unsigned int*)((char*)d_ws + rec_bytes);
        hipMemsetAsync(scale_u, 0, 4, stream);  // ws is poisoned 0xAA
        grid_absmax<<<512, 256, 0, stream>>>((const float4*)grid, scale_u);
        build_cells_i8<<<(NCELL + 255) / 256, 256, 0, stream>>>(grid, rec, scale_u);
        int blocks = (n + PPB - 1) / PPB;
        voxel_trilinear_i8<<<blocks, BLK, 0, stream>>>(x, rec, scale_u, out, n);
    } else if (ws_size >= (size_t)NVOX * sizeof(__half)) {
        __half* t = (__half*)d_ws;
        convert_grid_fp16<<<(NVOX + 255) / 256, 256, 0, stream>>>(grid, t);
        voxel_trilinear_pair<<<(n + 255) / 256, 256, 0, stream>>>(x, t, out, n);
    }
}